// Round 1
// baseline (1182.311 us; speedup 1.0000x reference)
//
#include <hip/hip_runtime.h>
#include <stdint.h>
#include <stddef.h>

// Problem constants
#define T_ 512
#define B_ 256
#define IN_ 292
#define H_ 128
#define G4_ 512   // 4*H
#define TB_ 131072  // T_*B_

typedef short bf16x8 __attribute__((ext_vector_type(8)));
typedef float f32x4 __attribute__((ext_vector_type(4)));

__device__ __forceinline__ unsigned short f2bf(float f) {
  unsigned u = __float_as_uint(f);
  u += 0x7FFFu + ((u >> 16) & 1u);   // RTNE
  return (unsigned short)(u >> 16);
}
__device__ __forceinline__ float bf2f(unsigned short s) {
  return __uint_as_float(((unsigned)s) << 16);
}
__device__ __forceinline__ bf16x8 pack8(float4 a, float4 b) {
  bf16x8 r;
  r[0]=(short)f2bf(a.x); r[1]=(short)f2bf(a.y); r[2]=(short)f2bf(a.z); r[3]=(short)f2bf(a.w);
  r[4]=(short)f2bf(b.x); r[5]=(short)f2bf(b.y); r[6]=(short)f2bf(b.z); r[7]=(short)f2bf(b.w);
  return r;
}
__device__ __forceinline__ float sigf(float x) {
  return __builtin_amdgcn_rcpf(1.0f + __expf(-x));
}
__device__ __forceinline__ float tanhf_(float x) {
  // 1 - 2/(exp(2x)+1); saturates correctly at +-inf
  return 1.0f - 2.0f * __builtin_amdgcn_rcpf(__expf(2.0f * x) + 1.0f);
}

// ---------------------------------------------------------------------------
// K1: pre[T*B][512] (bf16) = x @ W_ih^T + (b_ih + b_hh)
// Computed as D = W_ih * x^T so C-frag rows = gate index j (4 consecutive j
// per lane) and cols = row m -> 8B contiguous bf16 stores in [m][j] layout.
// Tiles: 128 m x 128 j per block, K padded 292->320 (10 x BK=32).
// ---------------------------------------------------------------------------
__global__ __launch_bounds__(256) void k1_pregemm(
    const float* __restrict__ x, const float* __restrict__ Wih,
    const float* __restrict__ bih, const float* __restrict__ bhh,
    unsigned short* __restrict__ pre) {
  __shared__ unsigned short xs[128 * 32];   // x tile  [m][k] bf16
  __shared__ unsigned short wsh[128 * 32];  // W tile  [j][k] bf16
  __shared__ float bias_s[128];

  const int m0 = blockIdx.x * 128;
  const int j0 = blockIdx.y * 128;
  const int tid = threadIdx.x;
  const int w = tid >> 6;
  const int lane = tid & 63;
  const int l15 = lane & 15;
  const int q = lane >> 4;
  const int jb = (w >> 1) * 64;  // wave's j sub-base
  const int mb = (w & 1) * 64;   // wave's m sub-base

  if (tid < 128) bias_s[tid] = bih[j0 + tid] + bhh[j0 + tid];

  f32x4 acc[4][4];  // [jsub][msub]
#pragma unroll
  for (int a = 0; a < 4; a++)
#pragma unroll
    for (int b = 0; b < 4; b++) acc[a][b] = (f32x4){0.f, 0.f, 0.f, 0.f};

  for (int kk = 0; kk < 320; kk += 32) {
    __syncthreads();  // prior-iter LDS reads done before restage
    if (kk < 288) {
      const int row = tid >> 1, half = tid & 1;
      const float* px = x + (size_t)(m0 + row) * IN_ + kk + half * 16;
      const float* pw = Wih + (size_t)(j0 + row) * IN_ + kk + half * 16;
      float4 a0 = *(const float4*)(px);      float4 a1 = *(const float4*)(px + 4);
      float4 a2 = *(const float4*)(px + 8);  float4 a3 = *(const float4*)(px + 12);
      float4 b0 = *(const float4*)(pw);      float4 b1 = *(const float4*)(pw + 4);
      float4 b2 = *(const float4*)(pw + 8);  float4 b3 = *(const float4*)(pw + 12);
      *(bf16x8*)&xs[row * 32 + half * 16]      = pack8(a0, a1);
      *(bf16x8*)&xs[row * 32 + half * 16 + 8]  = pack8(a2, a3);
      *(bf16x8*)&wsh[row * 32 + half * 16]     = pack8(b0, b1);
      *(bf16x8*)&wsh[row * 32 + half * 16 + 8] = pack8(b2, b3);
    } else {
      // k = 288..291 valid (exactly 4 floats to row end), rest zero
      if (tid < 128) {
        const int row = tid;
        float4 xa = *(const float4*)(x + (size_t)(m0 + row) * IN_ + 288);
        float4 wa = *(const float4*)(Wih + (size_t)(j0 + row) * IN_ + 288);
        float4 z4 = {0.f, 0.f, 0.f, 0.f};
        bf16x8 z8 = pack8(z4, z4);
        *(bf16x8*)&xs[row * 32]      = pack8(xa, z4);
        *(bf16x8*)&xs[row * 32 + 8]  = z8;
        *(bf16x8*)&xs[row * 32 + 16] = z8;
        *(bf16x8*)&xs[row * 32 + 24] = z8;
        *(bf16x8*)&wsh[row * 32]      = pack8(wa, z4);
        *(bf16x8*)&wsh[row * 32 + 8]  = z8;
        *(bf16x8*)&wsh[row * 32 + 16] = z8;
        *(bf16x8*)&wsh[row * 32 + 24] = z8;
      }
    }
    __syncthreads();
    bf16x8 af[4], bfr[4];
#pragma unroll
    for (int s = 0; s < 4; s++)
      af[s] = *(bf16x8*)&wsh[(jb + 16 * s + l15) * 32 + q * 8];
#pragma unroll
    for (int s = 0; s < 4; s++)
      bfr[s] = *(bf16x8*)&xs[(mb + 16 * s + l15) * 32 + q * 8];
#pragma unroll
    for (int js = 0; js < 4; js++)
#pragma unroll
      for (int ms = 0; ms < 4; ms++)
        acc[js][ms] = __builtin_amdgcn_mfma_f32_16x16x32_bf16(
            af[js], bfr[ms], acc[js][ms], 0, 0, 0);
  }

#pragma unroll
  for (int js = 0; js < 4; js++) {
    float4 bv = *(float4*)&bias_s[jb + 16 * js + 4 * q];
#pragma unroll
    for (int ms = 0; ms < 4; ms++) {
      const int m = m0 + mb + 16 * ms + l15;
      const int j = j0 + jb + 16 * js + 4 * q;
      ushort4 st;
      st.x = f2bf(acc[js][ms][0] + bv.x);
      st.y = f2bf(acc[js][ms][1] + bv.y);
      st.z = f2bf(acc[js][ms][2] + bv.z);
      st.w = f2bf(acc[js][ms][3] + bv.w);
      *(ushort4*)&pre[(size_t)m * G4_ + j] = st;
    }
  }
}

// ---------------------------------------------------------------------------
// K2: sequential LSTM over T. 16 blocks (one per 16-batch group), 512 thr.
// Wave w owns gate-tiles {w, w+8, w+16, w+24} => lane holds i,f,g,o for the
// same (b = lane&15, k = 16w + 4q + r) in-lane. W_hh resident in registers
// as bf16 A-frags. h in LDS (bf16, row pad 136). c in 4 VGPRs.
// ---------------------------------------------------------------------------
__global__ __launch_bounds__(512) void k2_lstm(
    const unsigned short* __restrict__ pre, const float* __restrict__ Whh,
    const float* __restrict__ h0, const float* __restrict__ c0,
    const int* __restrict__ done, unsigned short* __restrict__ hidden) {
  __shared__ unsigned short hs[16 * 136];
  __shared__ int dns[T_ * 16];  // done slice [t][b16], 32 KB

  const int bg = blockIdx.x;
  const int tid = threadIdx.x;
  const int w = tid >> 6;
  const int lane = tid & 63;
  const int l15 = lane & 15;
  const int q = lane >> 4;
  const int bglob = bg * 16 + l15;
  const int kcell = 16 * w + 4 * q;

  // stage done column slice: thread t -> 16 ints
  {
    const int* p = done + (size_t)tid * B_ + bg * 16;
    int4 d0 = *(const int4*)(p);     int4 d1 = *(const int4*)(p + 4);
    int4 d2 = *(const int4*)(p + 8); int4 d3 = *(const int4*)(p + 12);
    *(int4*)&dns[tid * 16]      = d0;
    *(int4*)&dns[tid * 16 + 4]  = d1;
    *(int4*)&dns[tid * 16 + 8]  = d2;
    *(int4*)&dns[tid * 16 + 12] = d3;
  }

  // resident W_hh A-frags: A[m=lane&15][k=q*8+j']
  bf16x8 wf[4][4];
#pragma unroll
  for (int tI = 0; tI < 4; tI++) {
    const int jg = 16 * (w + 8 * tI) + l15;
#pragma unroll
    for (int kc = 0; kc < 4; kc++) {
      const float* p = Whh + (size_t)jg * H_ + kc * 32 + q * 8;
      float4 u0 = *(const float4*)p;
      float4 u1 = *(const float4*)(p + 4);
      wf[tI][kc] = pack8(u0, u1);
    }
  }

  // c init (fp32 regs), h init -> LDS bf16
  float c_[4];
  {
    float4 cv = *(const float4*)(c0 + (size_t)bglob * H_ + kcell);
    c_[0] = cv.x; c_[1] = cv.y; c_[2] = cv.z; c_[3] = cv.w;
    const int b = tid >> 5, k = (tid & 31) * 4;
    float4 hv = *(const float4*)(h0 + (size_t)(bg * 16 + b) * H_ + k);
    ushort4 hp = {f2bf(hv.x), f2bf(hv.y), f2bf(hv.z), f2bf(hv.w)};
    *(ushort4*)&hs[b * 136 + k] = hp;
  }
  __syncthreads();

  // prefetch pre for t=0
  ushort4 pr[4], prn[4];
  {
    const unsigned short* pb = pre + (size_t)bglob * G4_;
#pragma unroll
    for (int tI = 0; tI < 4; tI++)
      pr[tI] = *(const ushort4*)&pb[16 * (w + 8 * tI) + 4 * q];
  }

  for (int t = 0; t < T_; t++) {
    // prefetch next step's pre (hidden behind MFMA + barrier)
    const int tn = (t + 1 < T_) ? t + 1 : T_ - 1;
    const unsigned short* pb = pre + ((size_t)tn * B_ + bglob) * G4_;
#pragma unroll
    for (int tI = 0; tI < 4; tI++)
      prn[tI] = *(const ushort4*)&pb[16 * (w + 8 * tI) + 4 * q];

    const int dn = dns[t * 16 + l15];

    // h B-frags from LDS, masked by done[t] (reset => h treated as 0)
    bf16x8 hf[4];
#pragma unroll
    for (int kc = 0; kc < 4; kc++) {
      bf16x8 v = *(bf16x8*)&hs[l15 * 136 + kc * 32 + q * 8];
      if (dn) v = (bf16x8){0, 0, 0, 0, 0, 0, 0, 0};
      hf[kc] = v;
    }

    f32x4 acc[4];
#pragma unroll
    for (int tI = 0; tI < 4; tI++) acc[tI] = (f32x4){0.f, 0.f, 0.f, 0.f};
#pragma unroll
    for (int tI = 0; tI < 4; tI++)
#pragma unroll
      for (int kc = 0; kc < 4; kc++)
        acc[tI] = __builtin_amdgcn_mfma_f32_16x16x32_bf16(
            wf[tI][kc], hf[kc], acc[tI], 0, 0, 0);

    __syncthreads();  // all h reads done before h rewrite

    const float m = dn ? 0.0f : 1.0f;
    ushort4 hw;
    unsigned short* hq = &hw.x;
#pragma unroll
    for (int r = 0; r < 4; r++) {
      const float iv = acc[0][r] + bf2f((&pr[0].x)[r]);
      const float fv = acc[1][r] + bf2f((&pr[1].x)[r]);
      const float gv = acc[2][r] + bf2f((&pr[2].x)[r]);
      const float ov = acc[3][r] + bf2f((&pr[3].x)[r]);
      float cc = c_[r] * m;
      cc = sigf(fv) * cc + sigf(iv) * tanhf_(gv);
      c_[r] = cc;
      hq[r] = f2bf(sigf(ov) * tanhf_(cc));
    }
    *(ushort4*)&hs[l15 * 136 + kcell] = hw;
    *(ushort4*)&hidden[((size_t)t * B_ + bglob) * H_ + kcell] = hw;
#pragma unroll
    for (int tI = 0; tI < 4; tI++) pr[tI] = prn[tI];
    __syncthreads();  // h visible before next step's reads
  }
}

// ---------------------------------------------------------------------------
// K3: out[T*B][13] = hidden @ [W_pi; W_v]^T + [b_pi; b_v]
// Block: 64 rows, 4 waves (16 rows each). W resident in A-frags (rows 13..15
// zero). D rows = output channel n, cols = m.
// ---------------------------------------------------------------------------
__global__ __launch_bounds__(256) void k3_head(
    const unsigned short* __restrict__ hidden, const float* __restrict__ Wpi,
    const float* __restrict__ bpi, const float* __restrict__ Wv,
    const float* __restrict__ bv, float* __restrict__ out) {
  __shared__ unsigned short hs3[64 * 136];
  __shared__ float bias_s[16];

  const int tid = threadIdx.x;
  const int w = tid >> 6;
  const int lane = tid & 63;
  const int l15 = lane & 15;
  const int q = lane >> 4;
  const int m0 = blockIdx.x * 64;

  if (tid < 16) bias_s[tid] = (tid < 12) ? bpi[tid] : ((tid == 12) ? bv[0] : 0.f);

  bf16x8 wf3[4];
#pragma unroll
  for (int kc = 0; kc < 4; kc++) {
    float4 u0 = {0.f, 0.f, 0.f, 0.f}, u1 = {0.f, 0.f, 0.f, 0.f};
    if (l15 < 12) {
      const float* p = Wpi + (size_t)l15 * H_ + kc * 32 + q * 8;
      u0 = *(const float4*)p; u1 = *(const float4*)(p + 4);
    } else if (l15 == 12) {
      const float* p = Wv + kc * 32 + q * 8;
      u0 = *(const float4*)p; u1 = *(const float4*)(p + 4);
    }
    wf3[kc] = pack8(u0, u1);
  }

  // stage 64 rows of hidden (bf16 passthrough)
  {
    const int row = tid >> 2, ks = (tid & 3) * 32;
    const unsigned short* p = hidden + (size_t)(m0 + row) * H_ + ks;
#pragma unroll
    for (int i = 0; i < 4; i++)
      *(uint4*)&hs3[row * 136 + ks + i * 8] = *(const uint4*)(p + i * 8);
  }
  __syncthreads();

  f32x4 acc = (f32x4){0.f, 0.f, 0.f, 0.f};
#pragma unroll
  for (int kc = 0; kc < 4; kc++) {
    bf16x8 hf = *(bf16x8*)&hs3[(16 * w + l15) * 136 + kc * 32 + q * 8];
    acc = __builtin_amdgcn_mfma_f32_16x16x32_bf16(wf3[kc], hf, acc, 0, 0, 0);
  }

  const float4 bb = *(float4*)&bias_s[4 * q];
  const int m = m0 + 16 * w + l15;
  const size_t ro = (size_t)m * 13;
  float v0 = acc[0] + bb.x, v1 = acc[1] + bb.y, v2 = acc[2] + bb.z, v3 = acc[3] + bb.w;
  if (q < 3) {
    out[ro + 4 * q + 0] = v0;
    out[ro + 4 * q + 1] = v1;
    out[ro + 4 * q + 2] = v2;
    out[ro + 4 * q + 3] = v3;
  } else {
    out[ro + 12] = v0;  // n == 12 (value); n = 13..15 dropped
  }
}

// ---------------------------------------------------------------------------
// Workspace layout (requires >= 160 MB):
//   pre    bf16 [131072][512]  : 134,217,728 B  @ offset 0
//   hidden bf16 [131072][128]  :  33,554,432 B  @ offset 134,217,728
// ---------------------------------------------------------------------------
extern "C" void kernel_launch(void* const* d_in, const int* in_sizes, int n_in,
                              void* d_out, int out_size, void* d_ws, size_t ws_size,
                              hipStream_t stream) {
  const float* x    = (const float*)d_in[0];
  const int* done   = (const int*)d_in[1];
  const float* h0   = (const float*)d_in[2];
  const float* c0   = (const float*)d_in[3];
  const float* Wih  = (const float*)d_in[4];
  const float* Whh  = (const float*)d_in[5];
  const float* bih  = (const float*)d_in[6];
  const float* bhh  = (const float*)d_in[7];
  const float* Wpi  = (const float*)d_in[8];
  const float* bpi  = (const float*)d_in[9];
  const float* Wv   = (const float*)d_in[10];
  const float* bv   = (const float*)d_in[11];
  (void)in_sizes; (void)n_in; (void)out_size; (void)ws_size;

  unsigned short* pre = (unsigned short*)d_ws;
  unsigned short* hidden = pre + (size_t)TB_ * G4_;
  float* out = (float*)d_out;

  k1_pregemm<<<dim3(TB_ / 128, G4_ / 128), 256, 0, stream>>>(x, Wih, bih, bhh, pre);
  k2_lstm<<<16, 512, 0, stream>>>(pre, Whh, h0, c0, done, hidden);
  k3_head<<<TB_ / 64, 256, 0, stream>>>(hidden, Wpi, bpi, Wv, bv, out);
}